// Round 8
// baseline (635.160 us; speedup 1.0000x reference)
//
#include <hip/hip_runtime.h>
#include <hip/hip_bf16.h>

#define NB 2
#define SS 1024
#define EE 512
#define HH 8
#define DD 64
#define LL 4
#define FFD 2048
#define VO 17
#define MM (NB*SS)
#define CH 64
#define NCH (SS/CH)   /* 16 chunks per sequence */
#define NHH (NB*HH)   /* 16 (n,h) pairs */
#define PD 68         /* padded LDS stride (fp32 attn tiles) */

typedef __attribute__((ext_vector_type(8))) short bshort8;
typedef __attribute__((ext_vector_type(4))) float f32x4;
typedef unsigned short u16;

__device__ __forceinline__ float b2f(u16 u) {
    return __uint_as_float(((unsigned)u) << 16);
}
__device__ __forceinline__ u16 f2b(float f) {
    unsigned u = __float_as_uint(f);
    u += 0x7fffu + ((u >> 16) & 1u);          // RNE to bf16 (finite inputs)
    return (u16)(u >> 16);
}

// ---------------- init: weight fp32->bf16 convert + embeddings, ONE dispatch ----------------
// blocks 0..6143: weight convert (2048 elems each); blocks 6144..8191: embed rows.
__global__ __launch_bounds__(256) void init_all(
    const int* __restrict__ seq, const int* __restrict__ dep,
    const int* __restrict__ pos, const float* __restrict__ tok,
    const float* __restrict__ dem, const float* __restrict__ sp,
    const float* __restrict__ sos,
    const float* __restrict__ Wq, const float* __restrict__ Wk,
    const float* __restrict__ Wv, const float* __restrict__ Wo,
    const float* __restrict__ W1, const float* __restrict__ W2,
    u16* __restrict__ dq, u16* __restrict__ dk, u16* __restrict__ dv,
    u16* __restrict__ do_, u16* __restrict__ d1, u16* __restrict__ d2,
    float* __restrict__ xf, u16* __restrict__ xh, float* __restrict__ mask)
{
    int b = blockIdx.x;
    int t = threadIdx.x;
    if (b < 6144) {
        const float* src; u16* dst; size_t off;
        if (b < 2048) {
            int r = b >> 9, o = b & 511;
            src = (r==0)?Wq:(r==1)?Wk:(r==2)?Wv:Wo;
            dst = (r==0)?dq:(r==1)?dk:(r==2)?dv:do_;
            off = (size_t)o * 2048;
        } else {
            int bb = b - 2048;
            int r = bb >> 11, o = bb & 2047;
            src = r ? W2 : W1;
            dst = r ? d2 : d1;
            off = (size_t)o * 2048;
        }
        size_t i = off + (size_t)t * 8;
        float4 v0 = *(const float4*)(src + i);
        float4 v1 = *(const float4*)(src + i + 4);
        bshort8 rr;
        rr[0]=(short)f2b(v0.x); rr[1]=(short)f2b(v0.y); rr[2]=(short)f2b(v0.z); rr[3]=(short)f2b(v0.w);
        rr[4]=(short)f2b(v1.x); rr[5]=(short)f2b(v1.y); rr[6]=(short)f2b(v1.z); rr[7]=(short)f2b(v1.w);
        *(bshort8*)(dst + i) = rr;
    } else {
        int m = b - 6144;
        int s = m % SS;
        if (t == 0) mask[m] = (seq[m] != 0) ? 1.0f : 0.0f;
        if (s == 0) {
            for (int e = t; e < EE; e += 256) {
                float v = sos[e];
                xf[(size_t)m*EE+e] = v; xh[(size_t)m*EE+e] = f2b(v);
            }
        } else {
            int mp = m - 1;
            int tk = seq[mp];
            int dh = dep[mp];
            int p0 = pos[0*NB*SS+mp], p1 = pos[1*NB*SS+mp], p2 = pos[2*NB*SS+mp];
            const float* r0 = tok + (size_t)tk*EE;
            const float* r1 = dem + (size_t)dh*EE;
            const float* r2 = sp + ((size_t)0*65 + p0)*EE;
            const float* r3 = sp + ((size_t)1*65 + p1)*EE;
            const float* r4 = sp + ((size_t)2*65 + p2)*EE;
            for (int e = t; e < EE; e += 256) {
                float v = r0[e] + r1[e] + r2[e] + r3[e] + r4[e];
                xf[(size_t)m*EE+e] = v; xh[(size_t)m*EE+e] = f2b(v);
            }
        }
    }
}

// ---------------- bf16 MFMA GEMM body (round-6 schedule) ----------------
// A: [*,Kstride] bf16 (pre-offset for split-K), W likewise. KL = loop K length.
// MODE 0: Ch = act(acc + bias) bf16;  MODE 2: Cf = acc fp32 partial.
// 64x64 tile, 4 waves x (32x32), double-buffered LDS, one barrier per K-tile;
// next-tile loads issued at top of iteration (fly during compute).
template<int ACT, int MODE>
__device__ __forceinline__ void gemm_body(
    const u16* __restrict__ A, const u16* __restrict__ W,
    int Kstride, int KL, const float* __restrict__ bias,
    u16* __restrict__ Ch, float* __restrict__ Cf,
    int m0, int n0, int Nn)
{
    __shared__ u16 sA[2][64][72];   // 144B row stride: 16B-aligned, ~2-way banks
    __shared__ u16 sB[2][64][72];
    int t = threadIdx.x;
    int lane = t & 63, w = t >> 6, wr = w >> 1, wc = w & 1;
    int l15 = lane & 15, lk = (lane >> 4) << 3;
    int sr = t >> 2, sc = (t & 3) << 4;          // 4 threads/row, 16 bf16 each
    const u16* Ap = A + (size_t)(m0 + sr) * Kstride + sc;
    const u16* Wp = W + (size_t)(n0 + sr) * Kstride + sc;
    int T = KL >> 6;
    bshort8 ra0 = *(const bshort8*)(Ap);
    bshort8 ra1 = *(const bshort8*)(Ap + 8);
    bshort8 rb0 = *(const bshort8*)(Wp);
    bshort8 rb1 = *(const bshort8*)(Wp + 8);
    *(bshort8*)&sA[0][sr][sc]   = ra0;  *(bshort8*)&sA[0][sr][sc+8] = ra1;
    *(bshort8*)&sB[0][sr][sc]   = rb0;  *(bshort8*)&sB[0][sr][sc+8] = rb1;
    __syncthreads();
    f32x4 acc[2][2] = {};
    for (int tt = 0; tt < T; ++tt) {
        int cur = tt & 1;
        bool more = (tt + 1 < T);
        if (more) {                               // issue next-tile loads early
            int kk = (tt + 1) << 6;
            ra0 = *(const bshort8*)(Ap + kk);
            ra1 = *(const bshort8*)(Ap + kk + 8);
            rb0 = *(const bshort8*)(Wp + kk);
            rb1 = *(const bshort8*)(Wp + kk + 8);
        }
        #pragma unroll
        for (int ks = 0; ks < 2; ++ks) {
            bshort8 af[2], bfr[2];
            #pragma unroll
            for (int mi=0;mi<2;++mi)
                af[mi] = *(const bshort8*)&sA[cur][wr*32+mi*16+l15][(ks<<5)+lk];
            #pragma unroll
            for (int ni=0;ni<2;++ni)
                bfr[ni] = *(const bshort8*)&sB[cur][wc*32+ni*16+l15][(ks<<5)+lk];
            #pragma unroll
            for (int mi=0;mi<2;++mi)
                #pragma unroll
                for (int ni=0;ni<2;++ni)
                    acc[mi][ni] = __builtin_amdgcn_mfma_f32_16x16x32_bf16(
                        af[mi], bfr[ni], acc[mi][ni], 0, 0, 0);
        }
        if (more) {
            int nxt = cur ^ 1;
            *(bshort8*)&sA[nxt][sr][sc]   = ra0;  *(bshort8*)&sA[nxt][sr][sc+8] = ra1;
            *(bshort8*)&sB[nxt][sr][sc]   = rb0;  *(bshort8*)&sB[nxt][sr][sc+8] = rb1;
            __syncthreads();                      // one barrier per K-tile
        }
    }
    int r0 = (lane >> 4) << 2;
    #pragma unroll
    for (int mi=0;mi<2;++mi) {
        #pragma unroll
        for (int ni=0;ni<2;++ni) {
            int col = n0 + wc*32 + ni*16 + l15;
            float bs = (MODE == 0) ? bias[col] : 0.f;
            #pragma unroll
            for (int r=0;r<4;++r) {
                int row = m0 + wr*32 + mi*16 + r0 + r;
                float v = acc[mi][ni][r] + bs;
                if (ACT == 1) v = 0.5f * v * (1.0f + erff(v * 0.70710678118654752f));
                if (MODE == 0) Ch[(size_t)row*Nn + col] = f2b(v);
                else           Cf[(size_t)row*Nn + col] = v;
            }
        }
    }
}

template<int ACT>
__global__ __launch_bounds__(256) void gemm_k(
    const u16* __restrict__ A, const u16* __restrict__ W,
    const float* __restrict__ bias, u16* __restrict__ Ch, int Nn, int K)
{
    gemm_body<ACT,0>(A, W, K, K, bias, Ch, nullptr, blockIdx.y*64, blockIdx.x*64, Nn);
}

// split-K x2 partial GEMM: blockIdx.z = K-half, fp32 partials
__global__ __launch_bounds__(256) void gemm_part(
    const u16* __restrict__ A, const u16* __restrict__ W,
    float* __restrict__ P, int Nn, int Kfull, int KL)
{
    int z = blockIdx.z;
    gemm_body<0,2>(A + (size_t)z*KL, W + (size_t)z*KL, Kfull, KL, nullptr,
                   nullptr, P + (size_t)z*MM*Nn, blockIdx.y*64, blockIdx.x*64, Nn);
}

// fused Q,K,V: blockIdx.z selects projection -> 3x grid, 3 blocks/CU
__global__ __launch_bounds__(256) void gemm_qkv(
    const u16* __restrict__ A,
    const u16* __restrict__ Wq, const u16* __restrict__ Wk, const u16* __restrict__ Wv,
    const float* __restrict__ bq, const float* __restrict__ bk, const float* __restrict__ bv,
    u16* __restrict__ qb, u16* __restrict__ kb, u16* __restrict__ vb, int Nn, int K)
{
    int z = blockIdx.z;
    const u16* W = (z==0) ? Wq : (z==1 ? Wk : Wv);
    const float* bias = (z==0) ? bq : (z==1 ? bk : bv);
    u16* Ch = (z==0) ? qb : (z==1 ? kb : vb);
    gemm_body<0,0>(A, W, K, K, bias, Ch, nullptr, blockIdx.y*64, blockIdx.x*64, Nn);
}

// ---------------- chunked linear attention, phase A: per-chunk KV = Kf^T V, zsum ----------------
__global__ __launch_bounds__(256) void attn_kv(
    const u16* __restrict__ kbuf, const u16* __restrict__ vbuf,
    const float* __restrict__ mask, float* __restrict__ kvc, float* __restrict__ zsum)
{
    int c = blockIdx.x, nh = blockIdx.y;
    int n = nh >> 3, h = nh & 7;
    __shared__ float sK[64][PD];
    __shared__ float sV[64][PD];
    int t = threadIdx.x;
    for (int idx = t; idx < 4096; idx += 256) {
        int i = idx >> 6, d = idx & 63;
        int m = n*SS + c*64 + i;
        float kk = b2f(kbuf[(size_t)m*EE + h*DD + d]);
        float f = kk > 0.f ? kk + 1.f : expf(kk);
        sK[i][d] = f * mask[m];
        sV[i][d] = b2f(vbuf[(size_t)m*EE + h*DD + d]);
    }
    __syncthreads();
    int tr = t >> 4, tc = t & 15;
    float acc[4][4] = {};
    for (int i = 0; i < 64; ++i) {
        float4 kd = *(const float4*)&sK[i][tr<<2];
        float4 vm = *(const float4*)&sV[i][tc<<2];
        float ka[4]={kd.x,kd.y,kd.z,kd.w}, vv[4]={vm.x,vm.y,vm.z,vm.w};
        #pragma unroll
        for (int a=0;a<4;++a)
            #pragma unroll
            for (int b=0;b<4;++b)
                acc[a][b] = fmaf(ka[a], vv[b], acc[a][b]);
    }
    size_t base = ((size_t)nh*NCH + c) * 4096;
    #pragma unroll
    for (int a=0;a<4;++a)
        *(float4*)&kvc[base + (size_t)((tr<<2)+a)*64 + (tc<<2)] =
            make_float4(acc[a][0],acc[a][1],acc[a][2],acc[a][3]);
    if (t < 64) {
        float z = 0.f;
        for (int i = 0; i < 64; ++i) z += sK[i][t];
        zsum[((size_t)nh*NCH + c)*64 + t] = z;
    }
}

// ---------------- phase C (prefix fused): intra-chunk causal + inter-chunk state ----------------
// kvc/zsum hold PER-CHUNK sums; each block forms its own exclusive prefix from L2.
__global__ __launch_bounds__(256) void attn_out(
    const u16* __restrict__ qbuf, const u16* __restrict__ kbuf,
    const u16* __restrict__ vbuf, const float* __restrict__ mask,
    const float* __restrict__ kvc, const float* __restrict__ zsum,
    u16* __restrict__ att)
{
    int c = blockIdx.x, nh = blockIdx.y;
    int n = nh >> 3, h = nh & 7;
    __shared__ float sQ[64][PD], sK[64][PD], sV[64][PD], sP[64][PD];
    __shared__ float sZ[64], sInv[64];
    __shared__ float sDen[64][4];
    int t = threadIdx.x;
    for (int idx = t; idx < 4096; idx += 256) {
        int i = idx >> 6, d = idx & 63;
        int m = n*SS + c*64 + i;
        float qq = b2f(qbuf[(size_t)m*EE + h*DD + d]);
        sQ[i][d] = qq > 0.f ? qq + 1.f : expf(qq);
        float kk = b2f(kbuf[(size_t)m*EE + h*DD + d]);
        float f = kk > 0.f ? kk + 1.f : expf(kk);
        sK[i][d] = f * mask[m];
        sV[i][d] = b2f(vbuf[(size_t)m*EE + h*DD + d]);
    }
    if (t < 64) {      // exclusive prefix of zsum over chunks < c
        float z = 0.f;
        size_t zb = (size_t)nh*NCH*64 + t;
        for (int cc = 0; cc < c; ++cc) z += zsum[zb + (size_t)cc*64];
        sZ[t] = z;
    }
    __syncthreads();
    int tr = t >> 4, tc = t & 15;
    // P = Qf @ Kf^T
    {
        float acc[4][4] = {};
        for (int d = 0; d < 64; d += 4) {
            float4 qa[4], kb4[4];
            #pragma unroll
            for (int a=0;a<4;++a) qa[a] = *(const float4*)&sQ[(tr<<2)+a][d];
            #pragma unroll
            for (int b=0;b<4;++b) kb4[b] = *(const float4*)&sK[(tc<<2)+b][d];
            #pragma unroll
            for (int a=0;a<4;++a) {
                float qv[4] = {qa[a].x,qa[a].y,qa[a].z,qa[a].w};
                #pragma unroll
                for (int b=0;b<4;++b) {
                    acc[a][b] += qv[0]*kb4[b].x + qv[1]*kb4[b].y
                               + qv[2]*kb4[b].z + qv[3]*kb4[b].w;
                }
            }
        }
        #pragma unroll
        for (int a=0;a<4;++a)
            *(float4*)&sP[(tr<<2)+a][tc<<2] =
                make_float4(acc[a][0],acc[a][1],acc[a][2],acc[a][3]);
    }
    __syncthreads();
    // stage inter-chunk state (exclusive prefix over chunks < c) into sK
    {
        size_t sb = (size_t)nh*NCH*4096;
        for (int idx = t; idx < 4096; idx += 256) {
            float s = 0.f;
            for (int cc = 0; cc < c; ++cc) s += kvc[sb + (size_t)cc*4096 + idx];
            sK[idx>>6][idx&63] = s;
        }
    }
    // parallel denominator partials: 4 threads per row
    {
        int rr = t & 63, qq = t >> 6;
        int j0 = qq << 4;
        float part = 0.f;
        #pragma unroll
        for (int j = 0; j < 16; ++j) {
            int jj = j0 + j;
            part += (jj <= rr) ? sP[rr][jj] : 0.f;
        }
        float dzp = 0.f;
        #pragma unroll
        for (int d = 0; d < 16; ++d) {
            int dd = j0 + d;
            dzp += sQ[rr][dd] * sZ[dd];
        }
        sDen[rr][qq] = part + dzp;
    }
    // intra-chunk causal: sum_{j<=i} P[i][j] * V[j][:]
    float acc1[4][4] = {};
    for (int j = 0; j < 64; ++j) {
        float4 vb4 = *(const float4*)&sV[j][tc<<2];
        float vv[4] = {vb4.x, vb4.y, vb4.z, vb4.w};
        #pragma unroll
        for (int a=0;a<4;++a) {
            int i = (tr<<2)+a;
            float p = (j <= i) ? sP[i][j] : 0.f;
            #pragma unroll
            for (int b=0;b<4;++b) acc1[a][b] = fmaf(p, vv[b], acc1[a][b]);
        }
    }
    __syncthreads();   // staged state + sDen ready
    if (t < 64)
        sInv[t] = 1.0f / (1e-6f + sDen[t][0] + sDen[t][1] + sDen[t][2] + sDen[t][3]);
    // inter-chunk: Qf @ State
    for (int d = 0; d < 64; ++d) {
        float4 sv4 = *(const float4*)&sK[d][tc<<2];
        float sv[4] = {sv4.x, sv4.y, sv4.z, sv4.w};
        #pragma unroll
        for (int a=0;a<4;++a) {
            float qv = sQ[(tr<<2)+a][d];
            #pragma unroll
            for (int b=0;b<4;++b) acc1[a][b] = fmaf(qv, sv[b], acc1[a][b]);
        }
    }
    __syncthreads();   // sInv visible to all
    #pragma unroll
    for (int a=0;a<4;++a) {
        int i = (tr<<2)+a;
        int m = n*SS + c*64 + i;
        float inv = sInv[i];
        size_t ob = (size_t)m*EE + h*DD + (tc<<2);
        att[ob+0] = f2b(acc1[a][0]*inv);
        att[ob+1] = f2b(acc1[a][1]*inv);
        att[ob+2] = f2b(acc1[a][2]*inv);
        att[ob+3] = f2b(acc1[a][3]*inv);
    }
}

// ---------------- fused LayerNorm: in = p0+p1 + bias + resid; dual fp32/bf16 out ----------------
__global__ __launch_bounds__(256) void ln_fuse2(
    const float* __restrict__ p0, const float* __restrict__ p1,
    const float* __restrict__ bias, const float* __restrict__ resid,
    const float* __restrict__ g, const float* __restrict__ b,
    float* __restrict__ outf, u16* __restrict__ outh)
{
    int m = blockIdx.x;
    int t = threadIdx.x;
    size_t i0 = (size_t)m*EE + t, i1 = i0 + 256;
    float v0 = p0[i0] + p1[i0] + bias[t]     + resid[i0];
    float v1 = p0[i1] + p1[i1] + bias[t+256] + resid[i1];
    float s = v0 + v1, sq = v0*v0 + v1*v1;
    for (int o = 32; o; o >>= 1) { s += __shfl_down(s, o); sq += __shfl_down(sq, o); }
    __shared__ float ws_[4], wq_[4];
    int w = t >> 6;
    if ((t & 63) == 0) { ws_[w] = s; wq_[w] = sq; }
    __syncthreads();
    if (t == 0) {
        float S=0.f, Q=0.f;
        for (int i=0;i<4;++i){S+=ws_[i];Q+=wq_[i];}
        float mean = S * (1.0f/512.0f);
        float var = Q * (1.0f/512.0f) - mean*mean;
        ws_[0] = mean; wq_[0] = rsqrtf(var + 1e-5f);
    }
    __syncthreads();
    float mean = ws_[0], inv = wq_[0];
    float o0 = (v0-mean)*inv*g[t]+b[t];
    float o1 = (v1-mean)*inv*g[t+256]+b[t+256];
    outf[i0] = o0;  outf[i1] = o1;
    outh[i0] = f2b(o0);  outh[i1] = f2b(o1);
}

// ---------------- final LN + head GEMM fused: 256 blocks x 8 rows ----------------
__global__ __launch_bounds__(256) void ln_head(
    const float* __restrict__ xf, const float* __restrict__ gf,
    const float* __restrict__ bfn, const float* __restrict__ Wh,
    float* __restrict__ out)
{
    __shared__ float sW[VO][516];   // padded: 516 dwords keeps 16B alignment, spreads banks
    __shared__ float sR[8][516];
    __shared__ float sMean[8], sRstd[8];
    int t = threadIdx.x;
    int m0 = blockIdx.x * 8;
    // stage Wh
    for (int i = t; i < VO*EE; i += 256) sW[i>>9][i&511] = Wh[i];
    // per-row stats: 32 threads per row
    {
        int r = t >> 5, l32 = t & 31;
        const float* row = xf + (size_t)(m0 + r) * EE;
        float s = 0.f, q = 0.f;
        for (int j = l32; j < EE; j += 32) { float v = row[j]; s += v; q += v*v; }
        for (int o = 16; o; o >>= 1) { s += __shfl_down(s, o, 32); q += __shfl_down(q, o, 32); }
        if (l32 == 0) {
            float mean = s * (1.0f/512.0f);
            float var = q * (1.0f/512.0f) - mean*mean;
            sMean[r] = mean; sRstd[r] = rsqrtf(var + 1e-5f);
        }
    }
    __syncthreads();
    // stage normalized rows
    for (int idx = t; idx < 8*EE; idx += 256) {
        int rr = idx >> 9, k = idx & 511;
        float v = xf[(size_t)(m0+rr)*EE + k];
        sR[rr][k] = (v - sMean[rr]) * sRstd[rr] * gf[k] + bfn[k];
    }
    __syncthreads();
    // 8 rows x 17 outputs = 136 dots
    if (t < 8*VO) {
        int r = t / VO, o = t % VO;
        float acc = 0.f;
        for (int k = 0; k < EE; k += 4) {
            float4 a = *(const float4*)&sR[r][k];
            float4 wv = *(const float4*)&sW[o][k];
            acc += a.x*wv.x + a.y*wv.y + a.z*wv.z + a.w*wv.w;
        }
        out[(size_t)(m0+r)*VO + o] = acc;
    }
}

extern "C" void kernel_launch(void* const* d_in, const int* in_sizes, int n_in,
                              void* d_out, int out_size, void* d_ws, size_t ws_size,
                              hipStream_t stream)
{
    (void)in_sizes; (void)n_in; (void)out_size; (void)ws_size;
    const int*   seq = (const int*)d_in[0];
    const int*   dep = (const int*)d_in[1];
    const int*   pos = (const int*)d_in[2];
    const float* tok = (const float*)d_in[3];
    const float* dem = (const float*)d_in[4];
    const float* sp  = (const float*)d_in[5];
    const float* sos = (const float*)d_in[6];
    const float* Wq  = (const float*)d_in[7];
    const float* bq  = (const float*)d_in[8];
    const float* Wk  = (const float*)d_in[9];
    const float* bk  = (const float*)d_in[10];
    const float* Wv  = (const float*)d_in[11];
    const float* bv  = (const float*)d_in[12];
    const float* Wo  = (const float*)d_in[13];
    const float* bo  = (const float*)d_in[14];
    const float* g1  = (const float*)d_in[15];
    const float* b1  = (const float*)d_in[16];
    const float* W1  = (const float*)d_in[17];
    const float* bf1 = (const float*)d_in[18];
    const float* W2  = (const float*)d_in[19];
    const float* bf2 = (const float*)d_in[20];
    const float* g2  = (const float*)d_in[21];
    const float* b2  = (const float*)d_in[22];
    const float* gf  = (const float*)d_in[23];
    const float* bfn = (const float*)d_in[24];
    const float* Wh  = (const float*)d_in[25];
    float* out = (float*)d_out;

    // -------- workspace layout --------
    float* xf    = (float*)d_ws;                   // MM*EE
    float* kvc   = xf   + (size_t)MM*EE;           // NHH*NCH*4096 (per-chunk sums)
    float* zsum  = kvc  + (size_t)NHH*NCH*DD*DD;   // NHH*NCH*64  (per-chunk sums)
    float* maskb = zsum + (size_t)NHH*NCH*DD;      // MM
    float* part  = maskb + MM;                     // 2 * MM*EE fp32 split-K partials
    u16* xh   = (u16*)(part + (size_t)2*MM*EE);    // MM*EE
    u16* qb   = xh + (size_t)MM*EE;                // union region: {qb,kb,vb,attb} / {h1}
    u16* kb   = qb + (size_t)MM*EE;
    u16* vb   = kb + (size_t)MM*EE;
    u16* attb = vb + (size_t)MM*EE;
    u16* h1   = qb;                                // overlay (4*MM*EE == MM*FFD)
    u16* wq16 = attb + (size_t)MM*EE;              // L*EE*EE each
    u16* wk16 = wq16 + (size_t)LL*EE*EE;
    u16* wv16 = wk16 + (size_t)LL*EE*EE;
    u16* wo16 = wv16 + (size_t)LL*EE*EE;
    u16* w116 = wo16 + (size_t)LL*EE*EE;           // L*FFD*EE
    u16* w216 = w116 + (size_t)LL*FFD*EE;          // L*FFD*EE

    dim3 blk(256);
    dim3 gQKV(EE/64, MM/64, 3);  // 768 blocks, 3/CU
    dim3 gF(FFD/64, MM/64);      // 1024 blocks, 4/CU
    dim3 gS(EE/64,  MM/64, 2);   // 512 blocks, 2/CU (split-K x2)
    dim3 gA(NCH, NHH);           // 256

    init_all<<<8192, blk, 0, stream>>>(seq, dep, pos, tok, dem, sp, sos,
                                       Wq, Wk, Wv, Wo, W1, W2,
                                       wq16, wk16, wv16, wo16, w116, w216,
                                       xf, xh, maskb);
    for (int l = 0; l < LL; ++l) {
        gemm_qkv<<<gQKV, blk, 0, stream>>>(
            xh, wq16 + (size_t)l*EE*EE, wk16 + (size_t)l*EE*EE, wv16 + (size_t)l*EE*EE,
            bq + (size_t)l*EE, bk + (size_t)l*EE, bv + (size_t)l*EE,
            qb, kb, vb, EE, EE);
        attn_kv<<<gA, blk, 0, stream>>>(kb, vb, maskb, kvc, zsum);
        attn_out<<<gA, blk, 0, stream>>>(qb, kb, vb, maskb, kvc, zsum, attb);
        gemm_part<<<gS, blk, 0, stream>>>(attb, wo16 + (size_t)l*EE*EE, part, EE, EE, EE/2);
        ln_fuse2<<<MM, blk, 0, stream>>>(part, part + (size_t)MM*EE, bo + (size_t)l*EE,
                                         xf, g1 + (size_t)l*EE, b1 + (size_t)l*EE, xf, xh);
        gemm_k<1><<<gF, blk, 0, stream>>>(xh, w116 + (size_t)l*FFD*EE,
                                          bf1 + (size_t)l*FFD, h1, FFD, EE);
        gemm_part<<<gS, blk, 0, stream>>>(h1, w216 + (size_t)l*EE*FFD, part, EE, FFD, FFD/2);
        ln_fuse2<<<MM, blk, 0, stream>>>(part, part + (size_t)MM*EE, bf2 + (size_t)l*EE,
                                         xf, g2 + (size_t)l*EE, b2 + (size_t)l*EE, xf, xh);
    }
    ln_head<<<MM/8, blk, 0, stream>>>(xf, gf, bfn, Wh, out);
}

// Round 9
// 464.665 us; speedup vs baseline: 1.3669x; 1.3669x over previous
//
#include <hip/hip_runtime.h>
#include <hip/hip_bf16.h>

#define NB 2
#define SS 1024
#define EE 512
#define HH 8
#define DD 64
#define LL 4
#define FFD 2048
#define VO 17
#define MM (NB*SS)
#define CH 64
#define NCH (SS/CH)   /* 16 chunks per sequence */
#define NHH (NB*HH)   /* 16 (n,h) pairs */
#define PD 68         /* padded LDS stride (fp32 attn tiles) */

typedef __attribute__((ext_vector_type(8))) short bshort8;
typedef __attribute__((ext_vector_type(4))) float f32x4;
typedef unsigned short u16;

__device__ __forceinline__ float b2f(u16 u) {
    return __uint_as_float(((unsigned)u) << 16);
}
__device__ __forceinline__ u16 f2b(float f) {
    unsigned u = __float_as_uint(f);
    u += 0x7fffu + ((u >> 16) & 1u);          // RNE to bf16 (finite inputs)
    return (u16)(u >> 16);
}

// ---------------- init: weight fp32->bf16 convert + embeddings, ONE dispatch ----------------
// blocks 0..6143: weight convert (2048 elems each); blocks 6144..8191: embed rows.
__global__ __launch_bounds__(256) void init_all(
    const int* __restrict__ seq, const int* __restrict__ dep,
    const int* __restrict__ pos, const float* __restrict__ tok,
    const float* __restrict__ dem, const float* __restrict__ sp,
    const float* __restrict__ sos,
    const float* __restrict__ Wq, const float* __restrict__ Wk,
    const float* __restrict__ Wv, const float* __restrict__ Wo,
    const float* __restrict__ W1, const float* __restrict__ W2,
    u16* __restrict__ dq, u16* __restrict__ dk, u16* __restrict__ dv,
    u16* __restrict__ do_, u16* __restrict__ d1, u16* __restrict__ d2,
    float* __restrict__ xf, u16* __restrict__ xh, float* __restrict__ mask)
{
    int b = blockIdx.x;
    int t = threadIdx.x;
    if (b < 6144) {
        const float* src; u16* dst; size_t off;
        if (b < 2048) {
            int r = b >> 9, o = b & 511;
            src = (r==0)?Wq:(r==1)?Wk:(r==2)?Wv:Wo;
            dst = (r==0)?dq:(r==1)?dk:(r==2)?dv:do_;
            off = (size_t)o * 2048;
        } else {
            int bb = b - 2048;
            int r = bb >> 11, o = bb & 2047;
            src = r ? W2 : W1;
            dst = r ? d2 : d1;
            off = (size_t)o * 2048;
        }
        size_t i = off + (size_t)t * 8;
        float4 v0 = *(const float4*)(src + i);
        float4 v1 = *(const float4*)(src + i + 4);
        bshort8 rr;
        rr[0]=(short)f2b(v0.x); rr[1]=(short)f2b(v0.y); rr[2]=(short)f2b(v0.z); rr[3]=(short)f2b(v0.w);
        rr[4]=(short)f2b(v1.x); rr[5]=(short)f2b(v1.y); rr[6]=(short)f2b(v1.z); rr[7]=(short)f2b(v1.w);
        *(bshort8*)(dst + i) = rr;
    } else {
        int m = b - 6144;
        int s = m % SS;
        if (t == 0) mask[m] = (seq[m] != 0) ? 1.0f : 0.0f;
        if (s == 0) {
            for (int e = t; e < EE; e += 256) {
                float v = sos[e];
                xf[(size_t)m*EE+e] = v; xh[(size_t)m*EE+e] = f2b(v);
            }
        } else {
            int mp = m - 1;
            int tk = seq[mp];
            int dh = dep[mp];
            int p0 = pos[0*NB*SS+mp], p1 = pos[1*NB*SS+mp], p2 = pos[2*NB*SS+mp];
            const float* r0 = tok + (size_t)tk*EE;
            const float* r1 = dem + (size_t)dh*EE;
            const float* r2 = sp + ((size_t)0*65 + p0)*EE;
            const float* r3 = sp + ((size_t)1*65 + p1)*EE;
            const float* r4 = sp + ((size_t)2*65 + p2)*EE;
            for (int e = t; e < EE; e += 256) {
                float v = r0[e] + r1[e] + r2[e] + r3[e] + r4[e];
                xf[(size_t)m*EE+e] = v; xh[(size_t)m*EE+e] = f2b(v);
            }
        }
    }
}

// ---------------- bf16 MFMA GEMM body (round-6 schedule) ----------------
// A: [*,Kstride] bf16 (pre-offset for split-K), W likewise. KL = loop K length.
// MODE 0: Ch = act(acc + bias) bf16;  MODE 2: Cf = acc fp32 partial.
// 64x64 tile, 4 waves x (32x32), double-buffered LDS, one barrier per K-tile;
// next-tile loads issued at top of iteration (fly during compute).
template<int ACT, int MODE>
__device__ __forceinline__ void gemm_body(
    const u16* __restrict__ A, const u16* __restrict__ W,
    int Kstride, int KL, const float* __restrict__ bias,
    u16* __restrict__ Ch, float* __restrict__ Cf,
    int m0, int n0, int Nn)
{
    __shared__ u16 sA[2][64][72];   // 144B row stride: 16B-aligned, ~2-way banks
    __shared__ u16 sB[2][64][72];
    int t = threadIdx.x;
    int lane = t & 63, w = t >> 6, wr = w >> 1, wc = w & 1;
    int l15 = lane & 15, lk = (lane >> 4) << 3;
    int sr = t >> 2, sc = (t & 3) << 4;          // 4 threads/row, 16 bf16 each
    const u16* Ap = A + (size_t)(m0 + sr) * Kstride + sc;
    const u16* Wp = W + (size_t)(n0 + sr) * Kstride + sc;
    int T = KL >> 6;
    bshort8 ra0 = *(const bshort8*)(Ap);
    bshort8 ra1 = *(const bshort8*)(Ap + 8);
    bshort8 rb0 = *(const bshort8*)(Wp);
    bshort8 rb1 = *(const bshort8*)(Wp + 8);
    *(bshort8*)&sA[0][sr][sc]   = ra0;  *(bshort8*)&sA[0][sr][sc+8] = ra1;
    *(bshort8*)&sB[0][sr][sc]   = rb0;  *(bshort8*)&sB[0][sr][sc+8] = rb1;
    __syncthreads();
    f32x4 acc[2][2] = {};
    for (int tt = 0; tt < T; ++tt) {
        int cur = tt & 1;
        bool more = (tt + 1 < T);
        if (more) {                               // issue next-tile loads early
            int kk = (tt + 1) << 6;
            ra0 = *(const bshort8*)(Ap + kk);
            ra1 = *(const bshort8*)(Ap + kk + 8);
            rb0 = *(const bshort8*)(Wp + kk);
            rb1 = *(const bshort8*)(Wp + kk + 8);
        }
        #pragma unroll
        for (int ks = 0; ks < 2; ++ks) {
            bshort8 af[2], bfr[2];
            #pragma unroll
            for (int mi=0;mi<2;++mi)
                af[mi] = *(const bshort8*)&sA[cur][wr*32+mi*16+l15][(ks<<5)+lk];
            #pragma unroll
            for (int ni=0;ni<2;++ni)
                bfr[ni] = *(const bshort8*)&sB[cur][wc*32+ni*16+l15][(ks<<5)+lk];
            #pragma unroll
            for (int mi=0;mi<2;++mi)
                #pragma unroll
                for (int ni=0;ni<2;++ni)
                    acc[mi][ni] = __builtin_amdgcn_mfma_f32_16x16x32_bf16(
                        af[mi], bfr[ni], acc[mi][ni], 0, 0, 0);
        }
        if (more) {
            int nxt = cur ^ 1;
            *(bshort8*)&sA[nxt][sr][sc]   = ra0;  *(bshort8*)&sA[nxt][sr][sc+8] = ra1;
            *(bshort8*)&sB[nxt][sr][sc]   = rb0;  *(bshort8*)&sB[nxt][sr][sc+8] = rb1;
            __syncthreads();                      // one barrier per K-tile
        }
    }
    int r0 = (lane >> 4) << 2;
    #pragma unroll
    for (int mi=0;mi<2;++mi) {
        #pragma unroll
        for (int ni=0;ni<2;++ni) {
            int col = n0 + wc*32 + ni*16 + l15;
            float bs = (MODE == 0) ? bias[col] : 0.f;
            #pragma unroll
            for (int r=0;r<4;++r) {
                int row = m0 + wr*32 + mi*16 + r0 + r;
                float v = acc[mi][ni][r] + bs;
                if (ACT == 1) v = 0.5f * v * (1.0f + erff(v * 0.70710678118654752f));
                if (MODE == 0) Ch[(size_t)row*Nn + col] = f2b(v);
                else           Cf[(size_t)row*Nn + col] = v;
            }
        }
    }
}

template<int ACT>
__global__ __launch_bounds__(256) void gemm_k(
    const u16* __restrict__ A, const u16* __restrict__ W,
    const float* __restrict__ bias, u16* __restrict__ Ch, int Nn, int K)
{
    gemm_body<ACT,0>(A, W, K, K, bias, Ch, nullptr, blockIdx.y*64, blockIdx.x*64, Nn);
}

// split-K x2 partial GEMM: blockIdx.z = K-half, fp32 partials
__global__ __launch_bounds__(256) void gemm_part(
    const u16* __restrict__ A, const u16* __restrict__ W,
    float* __restrict__ P, int Nn, int Kfull, int KL)
{
    int z = blockIdx.z;
    gemm_body<0,2>(A + (size_t)z*KL, W + (size_t)z*KL, Kfull, KL, nullptr,
                   nullptr, P + (size_t)z*MM*Nn, blockIdx.y*64, blockIdx.x*64, Nn);
}

// fused Q,K,V: blockIdx.z selects projection -> 3x grid, 3 blocks/CU
__global__ __launch_bounds__(256) void gemm_qkv(
    const u16* __restrict__ A,
    const u16* __restrict__ Wq, const u16* __restrict__ Wk, const u16* __restrict__ Wv,
    const float* __restrict__ bq, const float* __restrict__ bk, const float* __restrict__ bv,
    u16* __restrict__ qb, u16* __restrict__ kb, u16* __restrict__ vb, int Nn, int K)
{
    int z = blockIdx.z;
    const u16* W = (z==0) ? Wq : (z==1 ? Wk : Wv);
    const float* bias = (z==0) ? bq : (z==1 ? bk : bv);
    u16* Ch = (z==0) ? qb : (z==1 ? kb : vb);
    gemm_body<0,0>(A, W, K, K, bias, Ch, nullptr, blockIdx.y*64, blockIdx.x*64, Nn);
}

// ---------------- chunked linear attention, phase A: per-chunk KV = Kf^T V, zsum ----------------
__global__ __launch_bounds__(256) void attn_kv(
    const u16* __restrict__ kbuf, const u16* __restrict__ vbuf,
    const float* __restrict__ mask, float* __restrict__ kvc, float* __restrict__ zsum)
{
    int c = blockIdx.x, nh = blockIdx.y;
    int n = nh >> 3, h = nh & 7;
    __shared__ float sK[64][PD];
    __shared__ float sV[64][PD];
    int t = threadIdx.x;
    for (int idx = t; idx < 4096; idx += 256) {
        int i = idx >> 6, d = idx & 63;
        int m = n*SS + c*64 + i;
        float kk = b2f(kbuf[(size_t)m*EE + h*DD + d]);
        float f = kk > 0.f ? kk + 1.f : expf(kk);
        sK[i][d] = f * mask[m];
        sV[i][d] = b2f(vbuf[(size_t)m*EE + h*DD + d]);
    }
    __syncthreads();
    int tr = t >> 4, tc = t & 15;
    float acc[4][4] = {};
    for (int i = 0; i < 64; ++i) {
        float4 kd = *(const float4*)&sK[i][tr<<2];
        float4 vm = *(const float4*)&sV[i][tc<<2];
        float ka[4]={kd.x,kd.y,kd.z,kd.w}, vv[4]={vm.x,vm.y,vm.z,vm.w};
        #pragma unroll
        for (int a=0;a<4;++a)
            #pragma unroll
            for (int b=0;b<4;++b)
                acc[a][b] = fmaf(ka[a], vv[b], acc[a][b]);
    }
    size_t base = ((size_t)nh*NCH + c) * 4096;
    #pragma unroll
    for (int a=0;a<4;++a)
        *(float4*)&kvc[base + (size_t)((tr<<2)+a)*64 + (tc<<2)] =
            make_float4(acc[a][0],acc[a][1],acc[a][2],acc[a][3]);
    if (t < 64) {
        float z = 0.f;
        for (int i = 0; i < 64; ++i) z += sK[i][t];
        zsum[((size_t)nh*NCH + c)*64 + t] = z;
    }
}

// ---------------- phase B: IN-PLACE exclusive prefix over chunks, PARALLEL ----------------
// grid (16 slices, NHH). Each thread owns one state element; 16 chunk loads are
// independent (pipelined), prefix in registers.
__global__ __launch_bounds__(256) void attn_prefix(
    float* __restrict__ kvc, float* __restrict__ zsum)
{
    int s = blockIdx.x, nh = blockIdx.y;
    int t = threadIdx.x;
    int idx = s * 256 + t;
    size_t base = (size_t)nh * NCH * 4096 + idx;
    float v[NCH];
    #pragma unroll
    for (int c = 0; c < NCH; ++c) v[c] = kvc[base + (size_t)c*4096];
    float run = 0.f;
    #pragma unroll
    for (int c = 0; c < NCH; ++c) {
        kvc[base + (size_t)c*4096] = run;
        run += v[c];
    }
    if (s == 0 && t < 64) {
        size_t zb = (size_t)nh * NCH * 64 + t;
        float zv[NCH];
        #pragma unroll
        for (int c = 0; c < NCH; ++c) zv[c] = zsum[zb + (size_t)c*64];
        float zr = 0.f;
        #pragma unroll
        for (int c = 0; c < NCH; ++c) {
            zsum[zb + (size_t)c*64] = zr;
            zr += zv[c];
        }
    }
}

// ---------------- phase C: intra-chunk causal + inter-chunk state, normalize ----------------
__global__ __launch_bounds__(256) void attn_out(
    const u16* __restrict__ qbuf, const u16* __restrict__ kbuf,
    const u16* __restrict__ vbuf, const float* __restrict__ mask,
    const float* __restrict__ stc, const float* __restrict__ zpref,
    u16* __restrict__ att)
{
    int c = blockIdx.x, nh = blockIdx.y;
    int n = nh >> 3, h = nh & 7;
    __shared__ float sQ[64][PD], sK[64][PD], sV[64][PD], sP[64][PD];
    __shared__ float sZ[64], sInv[64];
    __shared__ float sDen[64][4];
    int t = threadIdx.x;
    for (int idx = t; idx < 4096; idx += 256) {
        int i = idx >> 6, d = idx & 63;
        int m = n*SS + c*64 + i;
        float qq = b2f(qbuf[(size_t)m*EE + h*DD + d]);
        sQ[i][d] = qq > 0.f ? qq + 1.f : expf(qq);
        float kk = b2f(kbuf[(size_t)m*EE + h*DD + d]);
        float f = kk > 0.f ? kk + 1.f : expf(kk);
        sK[i][d] = f * mask[m];
        sV[i][d] = b2f(vbuf[(size_t)m*EE + h*DD + d]);
    }
    if (t < 64) sZ[t] = zpref[((size_t)nh*NCH + c)*64 + t];
    __syncthreads();
    int tr = t >> 4, tc = t & 15;
    // P = Qf @ Kf^T
    {
        float acc[4][4] = {};
        for (int d = 0; d < 64; d += 4) {
            float4 qa[4], kb4[4];
            #pragma unroll
            for (int a=0;a<4;++a) qa[a] = *(const float4*)&sQ[(tr<<2)+a][d];
            #pragma unroll
            for (int b=0;b<4;++b) kb4[b] = *(const float4*)&sK[(tc<<2)+b][d];
            #pragma unroll
            for (int a=0;a<4;++a) {
                float qv[4] = {qa[a].x,qa[a].y,qa[a].z,qa[a].w};
                #pragma unroll
                for (int b=0;b<4;++b) {
                    acc[a][b] += qv[0]*kb4[b].x + qv[1]*kb4[b].y
                               + qv[2]*kb4[b].z + qv[3]*kb4[b].w;
                }
            }
        }
        #pragma unroll
        for (int a=0;a<4;++a)
            *(float4*)&sP[(tr<<2)+a][tc<<2] =
                make_float4(acc[a][0],acc[a][1],acc[a][2],acc[a][3]);
    }
    __syncthreads();
    // stage inter-chunk state into sK (sK no longer needed)
    {
        size_t sb = ((size_t)nh*NCH + c) * 4096;
        for (int idx = t; idx < 4096; idx += 256)
            sK[idx>>6][idx&63] = stc[sb + idx];
    }
    // parallel denominator partials: 4 threads per row
    {
        int rr = t & 63, qq = t >> 6;
        int j0 = qq << 4;
        float part = 0.f;
        #pragma unroll
        for (int j = 0; j < 16; ++j) {
            int jj = j0 + j;
            part += (jj <= rr) ? sP[rr][jj] : 0.f;
        }
        float dzp = 0.f;
        #pragma unroll
        for (int d = 0; d < 16; ++d) {
            int dd = j0 + d;
            dzp += sQ[rr][dd] * sZ[dd];
        }
        sDen[rr][qq] = part + dzp;
    }
    // intra-chunk causal: sum_{j<=i} P[i][j] * V[j][:]
    float acc1[4][4] = {};
    for (int j = 0; j < 64; ++j) {
        float4 vb4 = *(const float4*)&sV[j][tc<<2];
        float vv[4] = {vb4.x, vb4.y, vb4.z, vb4.w};
        #pragma unroll
        for (int a=0;a<4;++a) {
            int i = (tr<<2)+a;
            float p = (j <= i) ? sP[i][j] : 0.f;
            #pragma unroll
            for (int b=0;b<4;++b) acc1[a][b] = fmaf(p, vv[b], acc1[a][b]);
        }
    }
    __syncthreads();   // staged state + sDen ready
    if (t < 64)
        sInv[t] = 1.0f / (1e-6f + sDen[t][0] + sDen[t][1] + sDen[t][2] + sDen[t][3]);
    // inter-chunk: Qf @ State
    for (int d = 0; d < 64; ++d) {
        float4 sv4 = *(const float4*)&sK[d][tc<<2];
        float sv[4] = {sv4.x, sv4.y, sv4.z, sv4.w};
        #pragma unroll
        for (int a=0;a<4;++a) {
            float qv = sQ[(tr<<2)+a][d];
            #pragma unroll
            for (int b=0;b<4;++b) acc1[a][b] = fmaf(qv, sv[b], acc1[a][b]);
        }
    }
    __syncthreads();   // sInv visible to all
    #pragma unroll
    for (int a=0;a<4;++a) {
        int i = (tr<<2)+a;
        int m = n*SS + c*64 + i;
        float inv = sInv[i];
        size_t ob = (size_t)m*EE + h*DD + (tc<<2);
        att[ob+0] = f2b(acc1[a][0]*inv);
        att[ob+1] = f2b(acc1[a][1]*inv);
        att[ob+2] = f2b(acc1[a][2]*inv);
        att[ob+3] = f2b(acc1[a][3]*inv);
    }
}

// ---------------- fused LayerNorm: in = p0+p1 + bias + resid; dual fp32/bf16 out ----------------
__global__ __launch_bounds__(256) void ln_fuse2(
    const float* __restrict__ p0, const float* __restrict__ p1,
    const float* __restrict__ bias, const float* __restrict__ resid,
    const float* __restrict__ g, const float* __restrict__ b,
    float* __restrict__ outf, u16* __restrict__ outh)
{
    int m = blockIdx.x;
    int t = threadIdx.x;
    size_t i0 = (size_t)m*EE + t, i1 = i0 + 256;
    float v0 = p0[i0] + p1[i0] + bias[t]     + resid[i0];
    float v1 = p0[i1] + p1[i1] + bias[t+256] + resid[i1];
    float s = v0 + v1, sq = v0*v0 + v1*v1;
    for (int o = 32; o; o >>= 1) { s += __shfl_down(s, o); sq += __shfl_down(sq, o); }
    __shared__ float ws_[4], wq_[4];
    int w = t >> 6;
    if ((t & 63) == 0) { ws_[w] = s; wq_[w] = sq; }
    __syncthreads();
    if (t == 0) {
        float S=0.f, Q=0.f;
        for (int i=0;i<4;++i){S+=ws_[i];Q+=wq_[i];}
        float mean = S * (1.0f/512.0f);
        float var = Q * (1.0f/512.0f) - mean*mean;
        ws_[0] = mean; wq_[0] = rsqrtf(var + 1e-5f);
    }
    __syncthreads();
    float mean = ws_[0], inv = wq_[0];
    float o0 = (v0-mean)*inv*g[t]+b[t];
    float o1 = (v1-mean)*inv*g[t+256]+b[t+256];
    outf[i0] = o0;  outf[i1] = o1;
    outh[i0] = f2b(o0);  outh[i1] = f2b(o1);
}

// ---------------- final LN + head GEMM fused: 256 blocks x 8 rows ----------------
__global__ __launch_bounds__(256) void ln_head(
    const float* __restrict__ xf, const float* __restrict__ gf,
    const float* __restrict__ bfn, const float* __restrict__ Wh,
    float* __restrict__ out)
{
    __shared__ float sW[VO][516];   // padded: 516 dwords keeps 16B alignment, spreads banks
    __shared__ float sR[8][516];
    __shared__ float sMean[8], sRstd[8];
    int t = threadIdx.x;
    int m0 = blockIdx.x * 8;
    // stage Wh
    for (int i = t; i < VO*EE; i += 256) sW[i>>9][i&511] = Wh[i];
    // per-row stats: 32 threads per row
    {
        int r = t >> 5, l32 = t & 31;
        const float* row = xf + (size_t)(m0 + r) * EE;
        float s = 0.f, q = 0.f;
        for (int j = l32; j < EE; j += 32) { float v = row[j]; s += v; q += v*v; }
        for (int o = 16; o; o >>= 1) { s += __shfl_down(s, o, 32); q += __shfl_down(q, o, 32); }
        if (l32 == 0) {
            float mean = s * (1.0f/512.0f);
            float var = q * (1.0f/512.0f) - mean*mean;
            sMean[r] = mean; sRstd[r] = rsqrtf(var + 1e-5f);
        }
    }
    __syncthreads();
    // stage normalized rows
    for (int idx = t; idx < 8*EE; idx += 256) {
        int rr = idx >> 9, k = idx & 511;
        float v = xf[(size_t)(m0+rr)*EE + k];
        sR[rr][k] = (v - sMean[rr]) * sRstd[rr] * gf[k] + bfn[k];
    }
    __syncthreads();
    // 8 rows x 17 outputs = 136 dots
    if (t < 8*VO) {
        int r = t / VO, o = t % VO;
        float acc = 0.f;
        for (int k = 0; k < EE; k += 4) {
            float4 a = *(const float4*)&sR[r][k];
            float4 wv = *(const float4*)&sW[o][k];
            acc += a.x*wv.x + a.y*wv.y + a.z*wv.z + a.w*wv.w;
        }
        out[(size_t)(m0+r)*VO + o] = acc;
    }
}

extern "C" void kernel_launch(void* const* d_in, const int* in_sizes, int n_in,
                              void* d_out, int out_size, void* d_ws, size_t ws_size,
                              hipStream_t stream)
{
    (void)in_sizes; (void)n_in; (void)out_size; (void)ws_size;
    const int*   seq = (const int*)d_in[0];
    const int*   dep = (const int*)d_in[1];
    const int*   pos = (const int*)d_in[2];
    const float* tok = (const float*)d_in[3];
    const float* dem = (const float*)d_in[4];
    const float* sp  = (const float*)d_in[5];
    const float* sos = (const float*)d_in[6];
    const float* Wq  = (const float*)d_in[7];
    const float* bq  = (const float*)d_in[8];
    const float* Wk  = (const float*)d_in[9];
    const float* bk  = (const float*)d_in[10];
    const float* Wv  = (const float*)d_in[11];
    const float* bv  = (const float*)d_in[12];
    const float* Wo  = (const float*)d_in[13];
    const float* bo  = (const float*)d_in[14];
    const float* g1  = (const float*)d_in[15];
    const float* b1  = (const float*)d_in[16];
    const float* W1  = (const float*)d_in[17];
    const float* bf1 = (const float*)d_in[18];
    const float* W2  = (const float*)d_in[19];
    const float* bf2 = (const float*)d_in[20];
    const float* g2  = (const float*)d_in[21];
    const float* b2  = (const float*)d_in[22];
    const float* gf  = (const float*)d_in[23];
    const float* bfn = (const float*)d_in[24];
    const float* Wh  = (const float*)d_in[25];
    float* out = (float*)d_out;

    // -------- workspace layout --------
    float* xf    = (float*)d_ws;                   // MM*EE
    float* kvc   = xf   + (size_t)MM*EE;           // NHH*NCH*4096
    float* zsum  = kvc  + (size_t)NHH*NCH*DD*DD;   // NHH*NCH*64
    float* maskb = zsum + (size_t)NHH*NCH*DD;      // MM
    float* part  = maskb + MM;                     // 2 * MM*EE fp32 split-K partials
    u16* xh   = (u16*)(part + (size_t)2*MM*EE);    // MM*EE
    u16* qb   = xh + (size_t)MM*EE;                // union region: {qb,kb,vb,attb} / {h1}
    u16* kb   = qb + (size_t)MM*EE;
    u16* vb   = kb + (size_t)MM*EE;
    u16* attb = vb + (size_t)MM*EE;
    u16* h1   = qb;                                // overlay (4*MM*EE == MM*FFD)
    u16* wq16 = attb + (size_t)MM*EE;              // L*EE*EE each
    u16* wk16 = wq16 + (size_t)LL*EE*EE;
    u16* wv16 = wk16 + (size_t)LL*EE*EE;
    u16* wo16 = wv16 + (size_t)LL*EE*EE;
    u16* w116 = wo16 + (size_t)LL*EE*EE;           // L*FFD*EE
    u16* w216 = w116 + (size_t)LL*FFD*EE;          // L*FFD*EE

    dim3 blk(256);
    dim3 gQKV(EE/64, MM/64, 3);  // 768 blocks, 3/CU
    dim3 gF(FFD/64, MM/64);      // 1024 blocks, 4/CU
    dim3 gS(EE/64,  MM/64, 2);   // 512 blocks, 2/CU (split-K x2)
    dim3 gA(NCH, NHH);           // 256
    dim3 gP(NCH, NHH);           // 16 slices x 16 nh = 256 blocks

    init_all<<<8192, blk, 0, stream>>>(seq, dep, pos, tok, dem, sp, sos,
                                       Wq, Wk, Wv, Wo, W1, W2,
                                       wq16, wk16, wv16, wo16, w116, w216,
                                       xf, xh, maskb);
    for (int l = 0; l < LL; ++l) {
        gemm_qkv<<<gQKV, blk, 0, stream>>>(
            xh, wq16 + (size_t)l*EE*EE, wk16 + (size_t)l*EE*EE, wv16 + (size_t)l*EE*EE,
            bq + (size_t)l*EE, bk + (size_t)l*EE, bv + (size_t)l*EE,
            qb, kb, vb, EE, EE);
        attn_kv<<<gA, blk, 0, stream>>>(kb, vb, maskb, kvc, zsum);
        attn_prefix<<<gP, blk, 0, stream>>>(kvc, zsum);
        attn_out<<<gA, blk, 0, stream>>>(qb, kb, vb, maskb, kvc, zsum, attb);
        gemm_part<<<gS, blk, 0, stream>>>(attb, wo16 + (size_t)l*EE*EE, part, EE, EE, EE/2);
        ln_fuse2<<<MM, blk, 0, stream>>>(part, part + (size_t)MM*EE, bo + (size_t)l*EE,
                                         xf, g1 + (size_t)l*EE, b1 + (size_t)l*EE, xf, xh);
        gemm_k<1><<<gF, blk, 0, stream>>>(xh, w116 + (size_t)l*FFD*EE,
                                          bf1 + (size_t)l*FFD, h1, FFD, EE);
        gemm_part<<<gS, blk, 0, stream>>>(h1, w216 + (size_t)l*EE*FFD, part, EE, FFD, FFD/2);
        ln_fuse2<<<MM, blk, 0, stream>>>(part, part + (size_t)MM*EE, bf2 + (size_t)l*EE,
                                         xf, g2 + (size_t)l*EE, b2 + (size_t)l*EE, xf, xh);
    }
    ln_head<<<MM/8, blk, 0, stream>>>(xf, gf, bfn, Wh, out);
}

// Round 10
// 451.905 us; speedup vs baseline: 1.4055x; 1.0282x over previous
//
#include <hip/hip_runtime.h>
#include <hip/hip_bf16.h>

#define NB 2
#define SS 1024
#define EE 512
#define HH 8
#define DD 64
#define LL 4
#define FFD 2048
#define VO 17
#define MM (NB*SS)
#define CH 64
#define NCH (SS/CH)   /* 16 chunks per sequence */
#define NHH (NB*HH)   /* 16 (n,h) pairs */
#define PD 68         /* padded LDS stride (fp32 attn tiles) */

typedef __attribute__((ext_vector_type(8))) short bshort8;
typedef __attribute__((ext_vector_type(4))) float f32x4;
typedef unsigned short u16;

__device__ __forceinline__ float b2f(u16 u) {
    return __uint_as_float(((unsigned)u) << 16);
}
__device__ __forceinline__ u16 f2b(float f) {
    unsigned u = __float_as_uint(f);
    u += 0x7fffu + ((u >> 16) & 1u);          // RNE to bf16 (finite inputs)
    return (u16)(u >> 16);
}

// ---------------- init: weight fp32->bf16 convert + embeddings, ONE dispatch ----------------
// blocks 0..6143: weight convert (2048 elems each); blocks 6144..8191: embed rows.
__global__ __launch_bounds__(256) void init_all(
    const int* __restrict__ seq, const int* __restrict__ dep,
    const int* __restrict__ pos, const float* __restrict__ tok,
    const float* __restrict__ dem, const float* __restrict__ sp,
    const float* __restrict__ sos,
    const float* __restrict__ Wq, const float* __restrict__ Wk,
    const float* __restrict__ Wv, const float* __restrict__ Wo,
    const float* __restrict__ W1, const float* __restrict__ W2,
    u16* __restrict__ dq, u16* __restrict__ dk, u16* __restrict__ dv,
    u16* __restrict__ do_, u16* __restrict__ d1, u16* __restrict__ d2,
    u16* __restrict__ xh, float* __restrict__ mask)
{
    int b = blockIdx.x;
    int t = threadIdx.x;
    if (b < 6144) {
        const float* src; u16* dst; size_t off;
        if (b < 2048) {
            int r = b >> 9, o = b & 511;
            src = (r==0)?Wq:(r==1)?Wk:(r==2)?Wv:Wo;
            dst = (r==0)?dq:(r==1)?dk:(r==2)?dv:do_;
            off = (size_t)o * 2048;
        } else {
            int bb = b - 2048;
            int r = bb >> 11, o = bb & 2047;
            src = r ? W2 : W1;
            dst = r ? d2 : d1;
            off = (size_t)o * 2048;
        }
        size_t i = off + (size_t)t * 8;
        float4 v0 = *(const float4*)(src + i);
        float4 v1 = *(const float4*)(src + i + 4);
        bshort8 rr;
        rr[0]=(short)f2b(v0.x); rr[1]=(short)f2b(v0.y); rr[2]=(short)f2b(v0.z); rr[3]=(short)f2b(v0.w);
        rr[4]=(short)f2b(v1.x); rr[5]=(short)f2b(v1.y); rr[6]=(short)f2b(v1.z); rr[7]=(short)f2b(v1.w);
        *(bshort8*)(dst + i) = rr;
    } else {
        int m = b - 6144;
        int s = m % SS;
        if (t == 0) mask[m] = (seq[m] != 0) ? 1.0f : 0.0f;
        if (s == 0) {
            for (int e = t; e < EE; e += 256) xh[(size_t)m*EE+e] = f2b(sos[e]);
        } else {
            int mp = m - 1;
            int tk = seq[mp];
            int dh = dep[mp];
            int p0 = pos[0*NB*SS+mp], p1 = pos[1*NB*SS+mp], p2 = pos[2*NB*SS+mp];
            const float* r0 = tok + (size_t)tk*EE;
            const float* r1 = dem + (size_t)dh*EE;
            const float* r2 = sp + ((size_t)0*65 + p0)*EE;
            const float* r3 = sp + ((size_t)1*65 + p1)*EE;
            const float* r4 = sp + ((size_t)2*65 + p2)*EE;
            for (int e = t; e < EE; e += 256) {
                float v = r0[e] + r1[e] + r2[e] + r3[e] + r4[e];
                xh[(size_t)m*EE+e] = f2b(v);
            }
        }
    }
}

// ---------------- bf16 MFMA GEMM body (round-6 schedule) ----------------
// A: [*,Kstride] bf16 (pre-offset for split-K), W likewise. KL = loop K length.
// MODE 0: Ch = act(acc + bias) bf16;  MODE 2: Cf = acc fp32 partial.
// 64x64 tile, 4 waves x (32x32), double-buffered LDS, one barrier per K-tile;
// next-tile loads issued at top of iteration (fly during compute).
template<int ACT, int MODE>
__device__ __forceinline__ void gemm_body(
    const u16* __restrict__ A, const u16* __restrict__ W,
    int Kstride, int KL, const float* __restrict__ bias,
    u16* __restrict__ Ch, float* __restrict__ Cf,
    int m0, int n0, int Nn)
{
    __shared__ u16 sA[2][64][72];   // 144B row stride: 16B-aligned, ~2-way banks
    __shared__ u16 sB[2][64][72];
    int t = threadIdx.x;
    int lane = t & 63, w = t >> 6, wr = w >> 1, wc = w & 1;
    int l15 = lane & 15, lk = (lane >> 4) << 3;
    int sr = t >> 2, sc = (t & 3) << 4;          // 4 threads/row, 16 bf16 each
    const u16* Ap = A + (size_t)(m0 + sr) * Kstride + sc;
    const u16* Wp = W + (size_t)(n0 + sr) * Kstride + sc;
    int T = KL >> 6;
    bshort8 ra0 = *(const bshort8*)(Ap);
    bshort8 ra1 = *(const bshort8*)(Ap + 8);
    bshort8 rb0 = *(const bshort8*)(Wp);
    bshort8 rb1 = *(const bshort8*)(Wp + 8);
    *(bshort8*)&sA[0][sr][sc]   = ra0;  *(bshort8*)&sA[0][sr][sc+8] = ra1;
    *(bshort8*)&sB[0][sr][sc]   = rb0;  *(bshort8*)&sB[0][sr][sc+8] = rb1;
    __syncthreads();
    f32x4 acc[2][2] = {};
    for (int tt = 0; tt < T; ++tt) {
        int cur = tt & 1;
        bool more = (tt + 1 < T);
        if (more) {                               // issue next-tile loads early
            int kk = (tt + 1) << 6;
            ra0 = *(const bshort8*)(Ap + kk);
            ra1 = *(const bshort8*)(Ap + kk + 8);
            rb0 = *(const bshort8*)(Wp + kk);
            rb1 = *(const bshort8*)(Wp + kk + 8);
        }
        #pragma unroll
        for (int ks = 0; ks < 2; ++ks) {
            bshort8 af[2], bfr[2];
            #pragma unroll
            for (int mi=0;mi<2;++mi)
                af[mi] = *(const bshort8*)&sA[cur][wr*32+mi*16+l15][(ks<<5)+lk];
            #pragma unroll
            for (int ni=0;ni<2;++ni)
                bfr[ni] = *(const bshort8*)&sB[cur][wc*32+ni*16+l15][(ks<<5)+lk];
            #pragma unroll
            for (int mi=0;mi<2;++mi)
                #pragma unroll
                for (int ni=0;ni<2;++ni)
                    acc[mi][ni] = __builtin_amdgcn_mfma_f32_16x16x32_bf16(
                        af[mi], bfr[ni], acc[mi][ni], 0, 0, 0);
        }
        if (more) {
            int nxt = cur ^ 1;
            *(bshort8*)&sA[nxt][sr][sc]   = ra0;  *(bshort8*)&sA[nxt][sr][sc+8] = ra1;
            *(bshort8*)&sB[nxt][sr][sc]   = rb0;  *(bshort8*)&sB[nxt][sr][sc+8] = rb1;
            __syncthreads();                      // one barrier per K-tile
        }
    }
    int r0 = (lane >> 4) << 2;
    #pragma unroll
    for (int mi=0;mi<2;++mi) {
        #pragma unroll
        for (int ni=0;ni<2;++ni) {
            int col = n0 + wc*32 + ni*16 + l15;
            float bs = (MODE == 0) ? bias[col] : 0.f;
            #pragma unroll
            for (int r=0;r<4;++r) {
                int row = m0 + wr*32 + mi*16 + r0 + r;
                float v = acc[mi][ni][r] + bs;
                if (ACT == 1) v = 0.5f * v * (1.0f + erff(v * 0.70710678118654752f));
                if (MODE == 0) Ch[(size_t)row*Nn + col] = f2b(v);
                else           Cf[(size_t)row*Nn + col] = v;
            }
        }
    }
}

template<int ACT>
__global__ __launch_bounds__(256) void gemm_k(
    const u16* __restrict__ A, const u16* __restrict__ W,
    const float* __restrict__ bias, u16* __restrict__ Ch, int Nn, int K)
{
    gemm_body<ACT,0>(A, W, K, K, bias, Ch, nullptr, blockIdx.y*64, blockIdx.x*64, Nn);
}

// split-K x2 partial GEMM: blockIdx.z = K-half, fp32 partials
__global__ __launch_bounds__(256) void gemm_part(
    const u16* __restrict__ A, const u16* __restrict__ W,
    float* __restrict__ P, int Nn, int Kfull, int KL)
{
    int z = blockIdx.z;
    gemm_body<0,2>(A + (size_t)z*KL, W + (size_t)z*KL, Kfull, KL, nullptr,
                   nullptr, P + (size_t)z*MM*Nn, blockIdx.y*64, blockIdx.x*64, Nn);
}

// fused Q,K,V: blockIdx.z selects projection -> 3x grid, 3 blocks/CU
__global__ __launch_bounds__(256) void gemm_qkv(
    const u16* __restrict__ A,
    const u16* __restrict__ Wq, const u16* __restrict__ Wk, const u16* __restrict__ Wv,
    const float* __restrict__ bq, const float* __restrict__ bk, const float* __restrict__ bv,
    u16* __restrict__ qb, u16* __restrict__ kb, u16* __restrict__ vb, int Nn, int K)
{
    int z = blockIdx.z;
    const u16* W = (z==0) ? Wq : (z==1 ? Wk : Wv);
    const float* bias = (z==0) ? bq : (z==1 ? bk : bv);
    u16* Ch = (z==0) ? qb : (z==1 ? kb : vb);
    gemm_body<0,0>(A, W, K, K, bias, Ch, nullptr, blockIdx.y*64, blockIdx.x*64, Nn);
}

// ---------------- chunked linear attention, phase A: per-chunk KV = Kf^T V, zsum ----------------
// Vectorized staging: thread t -> row i = t>>2, d-block (t&3)*16 (two bshort8 per array).
__global__ __launch_bounds__(256) void attn_kv(
    const u16* __restrict__ kbuf, const u16* __restrict__ vbuf,
    const float* __restrict__ mask, float* __restrict__ kvc, float* __restrict__ zsum)
{
    int c = blockIdx.x, nh = blockIdx.y;
    int n = nh >> 3, h = nh & 7;
    __shared__ float sK[64][PD];
    __shared__ float sV[64][PD];
    int t = threadIdx.x;
    {
        int i = t >> 2, d0 = (t & 3) << 4;
        int m = n*SS + c*64 + i;
        size_t gb = (size_t)m*EE + h*DD + d0;
        bshort8 k0 = *(const bshort8*)&kbuf[gb];
        bshort8 k1 = *(const bshort8*)&kbuf[gb + 8];
        bshort8 v0 = *(const bshort8*)&vbuf[gb];
        bshort8 v1 = *(const bshort8*)&vbuf[gb + 8];
        float msk = mask[m];
        float kf[16], vf[16];
        #pragma unroll
        for (int j=0;j<8;++j) {
            float kk = b2f((u16)k0[j]);
            kf[j]   = (kk > 0.f ? kk + 1.f : expf(kk)) * msk;
            float k2 = b2f((u16)k1[j]);
            kf[j+8] = (k2 > 0.f ? k2 + 1.f : expf(k2)) * msk;
            vf[j]   = b2f((u16)v0[j]);
            vf[j+8] = b2f((u16)v1[j]);
        }
        #pragma unroll
        for (int j=0;j<4;++j) {
            *(float4*)&sK[i][d0 + j*4] = make_float4(kf[j*4],kf[j*4+1],kf[j*4+2],kf[j*4+3]);
            *(float4*)&sV[i][d0 + j*4] = make_float4(vf[j*4],vf[j*4+1],vf[j*4+2],vf[j*4+3]);
        }
    }
    __syncthreads();
    int tr = t >> 4, tc = t & 15;
    float acc[4][4] = {};
    for (int i = 0; i < 64; ++i) {
        float4 kd = *(const float4*)&sK[i][tr<<2];
        float4 vm = *(const float4*)&sV[i][tc<<2];
        float ka[4]={kd.x,kd.y,kd.z,kd.w}, vv[4]={vm.x,vm.y,vm.z,vm.w};
        #pragma unroll
        for (int a=0;a<4;++a)
            #pragma unroll
            for (int b=0;b<4;++b)
                acc[a][b] = fmaf(ka[a], vv[b], acc[a][b]);
    }
    size_t base = ((size_t)nh*NCH + c) * 4096;
    #pragma unroll
    for (int a=0;a<4;++a)
        *(float4*)&kvc[base + (size_t)((tr<<2)+a)*64 + (tc<<2)] =
            make_float4(acc[a][0],acc[a][1],acc[a][2],acc[a][3]);
    if (t < 64) {
        float z = 0.f;
        for (int i = 0; i < 64; ++i) z += sK[i][t];
        zsum[((size_t)nh*NCH + c)*64 + t] = z;
    }
}

// ---------------- phase B: IN-PLACE exclusive prefix over chunks, PARALLEL ----------------
__global__ __launch_bounds__(256) void attn_prefix(
    float* __restrict__ kvc, float* __restrict__ zsum)
{
    int s = blockIdx.x, nh = blockIdx.y;
    int t = threadIdx.x;
    int idx = s * 256 + t;
    size_t base = (size_t)nh * NCH * 4096 + idx;
    float v[NCH];
    #pragma unroll
    for (int c = 0; c < NCH; ++c) v[c] = kvc[base + (size_t)c*4096];
    float run = 0.f;
    #pragma unroll
    for (int c = 0; c < NCH; ++c) {
        kvc[base + (size_t)c*4096] = run;
        run += v[c];
    }
    if (s == 0 && t < 64) {
        size_t zb = (size_t)nh * NCH * 64 + t;
        float zv[NCH];
        #pragma unroll
        for (int c = 0; c < NCH; ++c) zv[c] = zsum[zb + (size_t)c*64];
        float zr = 0.f;
        #pragma unroll
        for (int c = 0; c < NCH; ++c) {
            zsum[zb + (size_t)c*64] = zr;
            zr += zv[c];
        }
    }
}

// ---------------- phase C: intra-chunk causal + inter-chunk state, normalize ----------------
__global__ __launch_bounds__(256) void attn_out(
    const u16* __restrict__ qbuf, const u16* __restrict__ kbuf,
    const u16* __restrict__ vbuf, const float* __restrict__ mask,
    const float* __restrict__ stc, const float* __restrict__ zpref,
    u16* __restrict__ att)
{
    int c = blockIdx.x, nh = blockIdx.y;
    int n = nh >> 3, h = nh & 7;
    __shared__ float sQ[64][PD], sK[64][PD], sV[64][PD], sP[64][PD];
    __shared__ float sZ[64], sInv[64];
    __shared__ float sDen[64][4];
    int t = threadIdx.x;
    {
        int i = t >> 2, d0 = (t & 3) << 4;
        int m = n*SS + c*64 + i;
        size_t gb = (size_t)m*EE + h*DD + d0;
        bshort8 q0 = *(const bshort8*)&qbuf[gb];
        bshort8 q1 = *(const bshort8*)&qbuf[gb + 8];
        bshort8 k0 = *(const bshort8*)&kbuf[gb];
        bshort8 k1 = *(const bshort8*)&kbuf[gb + 8];
        bshort8 v0 = *(const bshort8*)&vbuf[gb];
        bshort8 v1 = *(const bshort8*)&vbuf[gb + 8];
        float msk = mask[m];
        float qf[16], kf[16], vf[16];
        #pragma unroll
        for (int j=0;j<8;++j) {
            float qq = b2f((u16)q0[j]);
            qf[j]   = qq > 0.f ? qq + 1.f : expf(qq);
            float q2 = b2f((u16)q1[j]);
            qf[j+8] = q2 > 0.f ? q2 + 1.f : expf(q2);
            float kk = b2f((u16)k0[j]);
            kf[j]   = (kk > 0.f ? kk + 1.f : expf(kk)) * msk;
            float k2 = b2f((u16)k1[j]);
            kf[j+8] = (k2 > 0.f ? k2 + 1.f : expf(k2)) * msk;
            vf[j]   = b2f((u16)v0[j]);
            vf[j+8] = b2f((u16)v1[j]);
        }
        #pragma unroll
        for (int j=0;j<4;++j) {
            *(float4*)&sQ[i][d0 + j*4] = make_float4(qf[j*4],qf[j*4+1],qf[j*4+2],qf[j*4+3]);
            *(float4*)&sK[i][d0 + j*4] = make_float4(kf[j*4],kf[j*4+1],kf[j*4+2],kf[j*4+3]);
            *(float4*)&sV[i][d0 + j*4] = make_float4(vf[j*4],vf[j*4+1],vf[j*4+2],vf[j*4+3]);
        }
    }
    if (t < 64) sZ[t] = zpref[((size_t)nh*NCH + c)*64 + t];
    __syncthreads();
    int tr = t >> 4, tc = t & 15;
    // P = Qf @ Kf^T
    {
        float acc[4][4] = {};
        for (int d = 0; d < 64; d += 4) {
            float4 qa[4], kb4[4];
            #pragma unroll
            for (int a=0;a<4;++a) qa[a] = *(const float4*)&sQ[(tr<<2)+a][d];
            #pragma unroll
            for (int b=0;b<4;++b) kb4[b] = *(const float4*)&sK[(tc<<2)+b][d];
            #pragma unroll
            for (int a=0;a<4;++a) {
                float qv[4] = {qa[a].x,qa[a].y,qa[a].z,qa[a].w};
                #pragma unroll
                for (int b=0;b<4;++b) {
                    acc[a][b] += qv[0]*kb4[b].x + qv[1]*kb4[b].y
                               + qv[2]*kb4[b].z + qv[3]*kb4[b].w;
                }
            }
        }
        #pragma unroll
        for (int a=0;a<4;++a)
            *(float4*)&sP[(tr<<2)+a][tc<<2] =
                make_float4(acc[a][0],acc[a][1],acc[a][2],acc[a][3]);
    }
    __syncthreads();
    // stage inter-chunk state into sK (sK no longer needed)
    {
        size_t sb = ((size_t)nh*NCH + c) * 4096;
        for (int idx = t; idx < 4096; idx += 256)
            sK[idx>>6][idx&63] = stc[sb + idx];
    }
    // parallel denominator partials: 4 threads per row
    {
        int rr = t & 63, qq = t >> 6;
        int j0 = qq << 4;
        float part = 0.f;
        #pragma unroll
        for (int j = 0; j < 16; ++j) {
            int jj = j0 + j;
            part += (jj <= rr) ? sP[rr][jj] : 0.f;
        }
        float dzp = 0.f;
        #pragma unroll
        for (int d = 0; d < 16; ++d) {
            int dd = j0 + d;
            dzp += sQ[rr][dd] * sZ[dd];
        }
        sDen[rr][qq] = part + dzp;
    }
    // intra-chunk causal: sum_{j<=i} P[i][j] * V[j][:]
    float acc1[4][4] = {};
    for (int j = 0; j < 64; ++j) {
        float4 vb4 = *(const float4*)&sV[j][tc<<2];
        float vv[4] = {vb4.x, vb4.y, vb4.z, vb4.w};
        #pragma unroll
        for (int a=0;a<4;++a) {
            int i = (tr<<2)+a;
            float p = (j <= i) ? sP[i][j] : 0.f;
            #pragma unroll
            for (int b=0;b<4;++b) acc1[a][b] = fmaf(p, vv[b], acc1[a][b]);
        }
    }
    __syncthreads();   // staged state + sDen ready
    if (t < 64)
        sInv[t] = 1.0f / (1e-6f + sDen[t][0] + sDen[t][1] + sDen[t][2] + sDen[t][3]);
    // inter-chunk: Qf @ State
    for (int d = 0; d < 64; ++d) {
        float4 sv4 = *(const float4*)&sK[d][tc<<2];
        float sv[4] = {sv4.x, sv4.y, sv4.z, sv4.w};
        #pragma unroll
        for (int a=0;a<4;++a) {
            float qv = sQ[(tr<<2)+a][d];
            #pragma unroll
            for (int b=0;b<4;++b) acc1[a][b] = fmaf(qv, sv[b], acc1[a][b]);
        }
    }
    __syncthreads();   // sInv visible to all
    #pragma unroll
    for (int a=0;a<4;++a) {
        int i = (tr<<2)+a;
        int m = n*SS + c*64 + i;
        float inv = sInv[i];
        size_t ob = (size_t)m*EE + h*DD + (tc<<2);
        att[ob+0] = f2b(acc1[a][0]*inv);
        att[ob+1] = f2b(acc1[a][1]*inv);
        att[ob+2] = f2b(acc1[a][2]*inv);
        att[ob+3] = f2b(acc1[a][3]*inv);
    }
}

// ---------------- fused LayerNorm: in = p0+p1 + bias + bf16 resid; bf16 out ----------------
__global__ __launch_bounds__(256) void ln_fuse2(
    const float* __restrict__ p0, const float* __restrict__ p1,
    const float* __restrict__ bias, const u16* __restrict__ resid,
    const float* __restrict__ g, const float* __restrict__ b,
    u16* __restrict__ outh)
{
    int m = blockIdx.x;
    int t = threadIdx.x;
    size_t i0 = (size_t)m*EE + t, i1 = i0 + 256;
    float v0 = p0[i0] + p1[i0] + bias[t]     + b2f(resid[i0]);
    float v1 = p0[i1] + p1[i1] + bias[t+256] + b2f(resid[i1]);
    float s = v0 + v1, sq = v0*v0 + v1*v1;
    for (int o = 32; o; o >>= 1) { s += __shfl_down(s, o); sq += __shfl_down(sq, o); }
    __shared__ float ws_[4], wq_[4];
    int w = t >> 6;
    if ((t & 63) == 0) { ws_[w] = s; wq_[w] = sq; }
    __syncthreads();
    if (t == 0) {
        float S=0.f, Q=0.f;
        for (int i=0;i<4;++i){S+=ws_[i];Q+=wq_[i];}
        float mean = S * (1.0f/512.0f);
        float var = Q * (1.0f/512.0f) - mean*mean;
        ws_[0] = mean; wq_[0] = rsqrtf(var + 1e-5f);
    }
    __syncthreads();
    float mean = ws_[0], inv = wq_[0];
    outh[i0] = f2b((v0-mean)*inv*g[t]+b[t]);
    outh[i1] = f2b((v1-mean)*inv*g[t+256]+b[t+256]);
}

// ---------------- final LN + head GEMM fused: 256 blocks x 8 rows (bf16 input) ----------------
__global__ __launch_bounds__(256) void ln_head(
    const u16* __restrict__ xh, const float* __restrict__ gf,
    const float* __restrict__ bfn, const float* __restrict__ Wh,
    float* __restrict__ out)
{
    __shared__ float sW[VO][516];   // padded: 516 dwords keeps 16B alignment, spreads banks
    __shared__ float sR[8][516];
    __shared__ float sMean[8], sRstd[8];
    int t = threadIdx.x;
    int m0 = blockIdx.x * 8;
    // stage Wh
    for (int i = t; i < VO*EE; i += 256) sW[i>>9][i&511] = Wh[i];
    // per-row stats: 32 threads per row
    {
        int r = t >> 5, l32 = t & 31;
        const u16* row = xh + (size_t)(m0 + r) * EE;
        float s = 0.f, q = 0.f;
        for (int j = l32; j < EE; j += 32) { float v = b2f(row[j]); s += v; q += v*v; }
        for (int o = 16; o; o >>= 1) { s += __shfl_down(s, o, 32); q += __shfl_down(q, o, 32); }
        if (l32 == 0) {
            float mean = s * (1.0f/512.0f);
            float var = q * (1.0f/512.0f) - mean*mean;
            sMean[r] = mean; sRstd[r] = rsqrtf(var + 1e-5f);
        }
    }
    __syncthreads();
    // stage normalized rows
    for (int idx = t; idx < 8*EE; idx += 256) {
        int rr = idx >> 9, k = idx & 511;
        float v = b2f(xh[(size_t)(m0+rr)*EE + k]);
        sR[rr][k] = (v - sMean[rr]) * sRstd[rr] * gf[k] + bfn[k];
    }
    __syncthreads();
    // 8 rows x 17 outputs = 136 dots
    if (t < 8*VO) {
        int r = t / VO, o = t % VO;
        float acc = 0.f;
        for (int k = 0; k < EE; k += 4) {
            float4 a = *(const float4*)&sR[r][k];
            float4 wv = *(const float4*)&sW[o][k];
            acc += a.x*wv.x + a.y*wv.y + a.z*wv.z + a.w*wv.w;
        }
        out[(size_t)(m0+r)*VO + o] = acc;
    }
}

extern "C" void kernel_launch(void* const* d_in, const int* in_sizes, int n_in,
                              void* d_out, int out_size, void* d_ws, size_t ws_size,
                              hipStream_t stream)
{
    (void)in_sizes; (void)n_in; (void)out_size; (void)ws_size;
    const int*   seq = (const int*)d_in[0];
    const int*   dep = (const int*)d_in[1];
    const int*   pos = (const int*)d_in[2];
    const float* tok = (const float*)d_in[3];
    const float* dem = (const float*)d_in[4];
    const float* sp  = (const float*)d_in[5];
    const float* sos = (const float*)d_in[6];
    const float* Wq  = (const float*)d_in[7];
    const float* bq  = (const float*)d_in[8];
    const float* Wk  = (const float*)d_in[9];
    const float* bk  = (const float*)d_in[10];
    const float* Wv  = (const float*)d_in[11];
    const float* bv  = (const float*)d_in[12];
    const float* Wo  = (const float*)d_in[13];
    const float* bo  = (const float*)d_in[14];
    const float* g1  = (const float*)d_in[15];
    const float* b1  = (const float*)d_in[16];
    const float* W1  = (const float*)d_in[17];
    const float* bf1 = (const float*)d_in[18];
    const float* W2  = (const float*)d_in[19];
    const float* bf2 = (const float*)d_in[20];
    const float* g2  = (const float*)d_in[21];
    const float* b2  = (const float*)d_in[22];
    const float* gf  = (const float*)d_in[23];
    const float* bfn = (const float*)d_in[24];
    const float* Wh  = (const float*)d_in[25];
    float* out = (float*)d_out;

    // -------- workspace layout --------
    float* kvc   = (float*)d_ws;                   // NHH*NCH*4096
    float* zsum  = kvc  + (size_t)NHH*NCH*DD*DD;   // NHH*NCH*64
    float* maskb = zsum + (size_t)NHH*NCH*DD;      // MM
    float* part  = maskb + MM;                     // 2 * MM*EE fp32 split-K partials
    u16* xh   = (u16*)(part + (size_t)2*MM*EE);    // MM*EE (bf16 activations+resid)
    u16* qb   = xh + (size_t)MM*EE;                // union region: {qb,kb,vb,attb} / {h1}
    u16* kb   = qb + (size_t)MM*EE;
    u16* vb   = kb + (size_t)MM*EE;
    u16* attb = vb + (size_t)MM*EE;
    u16* h1   = qb;                                // overlay (4*MM*EE == MM*FFD)
    u16* wq16 = attb + (size_t)MM*EE;              // L*EE*EE each
    u16* wk16 = wq16 + (size_t)LL*EE*EE;
    u16* wv16 = wk16 + (size_t)LL*EE*EE;
    u16* wo16 = wv16 + (size_t)LL*EE*EE;
    u16* w116 = wo16 + (size_t)LL*EE*EE;           // L*FFD*EE
    u16* w216 = w116 + (size_t)LL*FFD*EE;          // L*FFD*EE

    dim3 blk(256);
    dim3 gQKV(EE/64, MM/64, 3);  // 768 blocks, 3/CU
    dim3 gF(FFD/64, MM/64);      // 1024 blocks, 4/CU
    dim3 gS(EE/64,  MM/64, 2);   // 512 blocks, 2/CU (split-K x2)
    dim3 gA(NCH, NHH);           // 256
    dim3 gP(NCH, NHH);           // 16 slices x 16 nh = 256 blocks

    init_all<<<8192, blk, 0, stream>>>(seq, dep, pos, tok, dem, sp, sos,
                                       Wq, Wk, Wv, Wo, W1, W2,
                                       wq16, wk16, wv16, wo16, w116, w216,
                                       xh, maskb);
    for (int l = 0; l < LL; ++l) {
        gemm_qkv<<<gQKV, blk, 0, stream>>>(
            xh, wq16 + (size_t)l*EE*EE, wk16 + (size_t)l*EE*EE, wv16 + (size_t)l*EE*EE,
            bq + (size_t)l*EE, bk + (size_t)l*EE, bv + (size_t)l*EE,
            qb, kb, vb, EE, EE);
        attn_kv<<<gA, blk, 0, stream>>>(kb, vb, maskb, kvc, zsum);
        attn_prefix<<<gP, blk, 0, stream>>>(kvc, zsum);
        attn_out<<<gA, blk, 0, stream>>>(qb, kb, vb, maskb, kvc, zsum, attb);
        gemm_part<<<gS, blk, 0, stream>>>(attb, wo16 + (size_t)l*EE*EE, part, EE, EE, EE/2);
        ln_fuse2<<<MM, blk, 0, stream>>>(part, part + (size_t)MM*EE, bo + (size_t)l*EE,
                                         xh, g1 + (size_t)l*EE, b1 + (size_t)l*EE, xh);
        gemm_k<1><<<gF, blk, 0, stream>>>(xh, w116 + (size_t)l*FFD*EE,
                                          bf1 + (size_t)l*FFD, h1, FFD, EE);
        gemm_part<<<gS, blk, 0, stream>>>(h1, w216 + (size_t)l*EE*FFD, part, EE, FFD, FFD/2);
        ln_fuse2<<<MM, blk, 0, stream>>>(part, part + (size_t)MM*EE, bf2 + (size_t)l*EE,
                                         xh, g2 + (size_t)l*EE, b2 + (size_t)l*EE, xh);
    }
    ln_head<<<MM/8, blk, 0, stream>>>(xh, gf, bfn, Wh, out);
}